// Round 10
// baseline (209.641 us; speedup 1.0000x reference)
//
#include <hip/hip_runtime.h>
#include <stdint.h>

// ---------------------------------------------------------------------------
// GraphRec forward, MI355X.
//  K1 k_mlp  : e_r + 2-layer MLPs -> Uh,Vh (f32) + blocked bf16 copies
//  K2 k_gemm : merged, interleaved (bid%3==0 -> Q, else P):
//    Q: R^T@Uh. Counted-vmcnt pipeline, 2-deep 20KB LDS buffers (40KB total ->
//       4 blocks/CU) holding BOTH the A tile (16KB) and B slice (4KB); in-loop
//       B reads are ds_read so the vmcnt queue stays pure staging.
//       vmcnt(5) steady state; tail vmcnt(5)/vmcnt(0).
//    P: P_I = R[bu]@Vh, P_S = S[bu]@Uh. 8 k-slabs, depth-4 f32 reg pipeline,
//       B direct from global blocked bf16 (L2-hot).
//    All f32->bf16 via v_cvt_pk_bf16_f32 (1 VALU op per 2 floats).
//  S1 k_scoreAM  : pre-softmax scores sA (cat(Vb,Ub)) and sM (cat(Ub,Vb))
//  S2 k_HI_scoreB: [softmax-A in-block] H_I = relu((A.P_I)@W_I+b); sB
//  S3 k_HS_H : [softmax-B] H_S = relu((B.P_S)@W_Sm+b); H = MLP(cat(H_I,H_S))
//  S4 k_Z_G  : [softmax-M] Z = relu((M.Q[bi])@W_Z+b); G = MLP(cat(H,Z))
// ---------------------------------------------------------------------------

typedef short bf16x8 __attribute__((ext_vector_type(8)));
typedef float f32x4 __attribute__((ext_vector_type(4)));

#define PKZ      8
#define PKLEN    1024        // 8192 / PKZ
#define PKITERS  32          // PKLEN / 32
#define QKZ      8
#define QSLAB    1024        // u rows per slab
#define QW       128         // i window per block
#define QSTEPS   32          // QSLAB / 32
#define QBLOCKS  512         // 64 iw x 8 kz
#define PBLOCKS  1024        // 2 * PKZ * 64

__device__ __forceinline__ unsigned cvt_pk_bf16(float lo, float hi) {
    unsigned r;
    asm("v_cvt_pk_bf16_f32 %0, %1, %2" : "=v"(r) : "v"(lo), "v"(hi));
    return r;
}

__device__ __forceinline__ float wsum(float v) {
    #pragma unroll
    for (int o = 32; o; o >>= 1) v += __shfl_xor(v, o);
    return v;
}

// block-wide softmax stats over a 4096-vector (256-thread block)
__device__ __forceinline__ void block_softmax_stats(const float* __restrict__ s,
                                                    float& m, float& inv) {
    __shared__ float r1[4];
    __shared__ float r2[4];
    int t = threadIdx.x, lane = t & 63, wv = t >> 6;
    float lm = -3.4e38f;
    #pragma unroll
    for (int i = 0; i < 16; ++i) lm = fmaxf(lm, s[t + 256 * i]);
    #pragma unroll
    for (int o = 32; o; o >>= 1) lm = fmaxf(lm, __shfl_xor(lm, o));
    if (lane == 0) r1[wv] = lm;
    __syncthreads();
    m = fmaxf(fmaxf(r1[0], r1[1]), fmaxf(r1[2], r1[3]));
    float ls = 0.f;
    #pragma unroll
    for (int i = 0; i < 16; ++i) ls += __expf(s[t + 256 * i] - m);
    ls = wsum(ls);
    if (lane == 0) r2[wv] = ls;
    __syncthreads();
    inv = 1.f / (r2[0] + r2[1] + r2[2] + r2[3]);
}

// ---------------------------------------------------------------- K1: MLPs
__global__ __launch_bounds__(256) void k_mlp(
    const float* __restrict__ U, const float* __restrict__ V,
    const float* __restrict__ w_r, const float* __restrict__ b_r,
    const float* __restrict__ Wu0, const float* __restrict__ bu0,
    const float* __restrict__ Wu1, const float* __restrict__ bu1,
    const float* __restrict__ Wv0, const float* __restrict__ bv0,
    const float* __restrict__ Wv1, const float* __restrict__ bv1,
    float* __restrict__ Uh, float* __restrict__ Vh,
    unsigned short* __restrict__ Uhb, unsigned short* __restrict__ Vhb)
{
    int gt = blockIdx.x * 256 + threadIdx.x;
    int wid = gt >> 6;
    int lane = gt & 63;

    float er = b_r[lane];
    #pragma unroll
    for (int s = 0; s < 5; ++s) er += (float)(s + 1) * w_r[s * 64 + lane];

    const int isV = (wid >= 2048);
    const float* X  = isV ? V   : U;
    const float* W0 = isV ? Wv0 : Wu0;
    const float* B0 = isV ? bv0 : bu0;
    const float* W1 = isV ? Wv1 : Wu1;
    const float* B1 = isV ? bv1 : bu1;
    float* Hout          = isV ? Vh  : Uh;
    unsigned short* Hb   = isV ? Vhb : Uhb;
    int r0 = (wid & 2047) * 4;

    float x[4];
    #pragma unroll
    for (int j = 0; j < 4; ++j) x[j] = X[(r0 + j) * 64 + lane];

    float h0c = B0[lane];
    for (int k = 0; k < 64; ++k) h0c += __shfl(er, k) * W0[(64 + k) * 64 + lane];

    float h0[4];
    #pragma unroll
    for (int j = 0; j < 4; ++j) h0[j] = h0c;
    for (int k = 0; k < 64; ++k) {
        float wv = W0[k * 64 + lane];
        #pragma unroll
        for (int j = 0; j < 4; ++j) h0[j] += __shfl(x[j], k) * wv;
    }
    #pragma unroll
    for (int j = 0; j < 4; ++j) h0[j] = fmaxf(h0[j], 0.f);

    float h1[4];
    #pragma unroll
    for (int j = 0; j < 4; ++j) h1[j] = B1[lane];
    for (int k = 0; k < 64; ++k) {
        float wv = W1[k * 64 + lane];
        #pragma unroll
        for (int j = 0; j < 4; ++j) h1[j] += __shfl(h0[j], k) * wv;
    }
    #pragma unroll
    for (int j = 0; j < 4; ++j) {
        h1[j] = fmaxf(h1[j], 0.f);
        Hout[(r0 + j) * 64 + lane] = h1[j];
    }
    // blocked bf16: element (r,d) at (r>>3)*512 + (d>>4)*128 + (d&15)*8 + (r&7)
    unsigned pw[2];
    pw[0] = cvt_pk_bf16(h1[0], h1[1]);
    pw[1] = cvt_pk_bf16(h1[2], h1[3]);
    unsigned short* dst = Hb + (size_t)(r0 >> 3) * 512 + (lane >> 4) * 128
                        + (lane & 15) * 8 + (r0 & 7);
    *(uint2*)dst = make_uint2(pw[0], pw[1]);
}

// --------------------------------------------------------------- K2: GEMMs
__global__ __launch_bounds__(256) void k_gemm(
    const float* __restrict__ R, const float* __restrict__ S,
    const int* __restrict__ bu,
    const unsigned short* __restrict__ Uhb, const unsigned short* __restrict__ Vhb,
    float* __restrict__ PpI, float* __restrict__ PpS, float* __restrict__ Qp)
{
    __shared__ alignas(16) char QLDS[2][20480];   // 40 KB: 16KB A + 4KB B per buf
    const int bid = blockIdx.x;
    const int t = threadIdx.x;
    const int w = t >> 6, l = t & 63, lg = l >> 4, lr = l & 15;

    if (bid % 3 == 0) {
        // ---------------- Q path: Q = R^T @ Uh
        const int qidx = bid / 3;          // 0..511
        const int iw = qidx & 63;
        const int kz = qidx >> 6;          // 0..7
        const int i0 = iw * QW;
        const int u0 = kz * QSLAB;

        f32x4 acc[2][4] = {};

        // stage step s into QLDS[s%2]: A tile [32u x 128i] f32 (wave w inst q
        // covers rows 2*(4q+w)..+1, 512 B contiguous each) + B slice 4 KB
        // (blocked Uhb rows u0+32s..+32, wave w stages bytes w*1024..+1024).
        #define QSTAGE(s)                                                         \
        {                                                                         \
            char* dstA = QLDS[(s) & 1];                                           \
            _Pragma("unroll")                                                     \
            for (int q = 0; q < 4; ++q) {                                         \
                const int rloc = 2 * (4 * q + w);                                 \
                const float* g = R + ((size_t)(u0 + (s) * 32 + rloc) + (l >> 5)) * 8192 \
                               + i0 + (l & 31) * 4;                               \
                __builtin_amdgcn_global_load_lds(                                 \
                    (const __attribute__((address_space(1))) void*)g,             \
                    (__attribute__((address_space(3))) void*)(dstA + rloc * 512 + l * 16), \
                    16, 0, 0);                                                    \
            }                                                                     \
            const char* bsrc = (const char*)Uhb                                   \
                + ((size_t)((u0 + (s) * 32) >> 3)) * 1024 + w * 1024 + l * 16;    \
            __builtin_amdgcn_global_load_lds(                                     \
                (const __attribute__((address_space(1))) void*)bsrc,              \
                (__attribute__((address_space(3))) void*)(dstA + 16384 + w * 1024 + l * 16), \
                16, 0, 0);                                                        \
        }

        #define QCOMP(s)                                                          \
        {                                                                         \
            const char* buf = QLDS[(s) & 1];                                      \
            const float* La = (const float*)buf;                                  \
            const short* Lbb = (const short*)(buf + 16384);                       \
            bf16x8 bfrag[4];                                                      \
            _Pragma("unroll")                                                     \
            for (int c = 0; c < 4; ++c)                                           \
                bfrag[c] = *(const bf16x8*)(Lbb + lg * 512 + c * 128 + lr * 8);   \
            _Pragma("unroll")                                                     \
            for (int f = 0; f < 2; ++f) {                                         \
                const int iloc = w * 32 + f * 16 + lr;                            \
                float av[8];                                                      \
                _Pragma("unroll")                                                 \
                for (int j = 0; j < 8; ++j) av[j] = La[(8 * lg + j) * QW + iloc]; \
                union { bf16x8 v; unsigned u[4]; } af;                            \
                _Pragma("unroll")                                                 \
                for (int qq = 0; qq < 4; ++qq)                                    \
                    af.u[qq] = cvt_pk_bf16(av[2*qq], av[2*qq+1]);                 \
                _Pragma("unroll")                                                 \
                for (int c = 0; c < 4; ++c)                                       \
                    acc[f][c] = __builtin_amdgcn_mfma_f32_16x16x32_bf16(af.v, bfrag[c], acc[f][c], 0, 0, 0); \
            }                                                                     \
        }

        QSTAGE(0); QSTAGE(1);                // 10 insts/wave in flight

        for (int s = 0; s < QSTEPS - 2; ++s) {
            // <=5 outstanding => oldest stage (5 insts) landed
            asm volatile("s_waitcnt vmcnt(5)" ::: "memory");
            __builtin_amdgcn_s_barrier();
            QCOMP(s);
            asm volatile("s_waitcnt lgkmcnt(0)" ::: "memory");
            __builtin_amdgcn_sched_barrier(0);
            __builtin_amdgcn_s_barrier();
            QSTAGE(s + 2);
        }
        asm volatile("s_waitcnt vmcnt(5)" ::: "memory");
        __builtin_amdgcn_s_barrier();
        QCOMP(QSTEPS - 2);
        asm volatile("s_waitcnt vmcnt(0)" ::: "memory");
        __builtin_amdgcn_s_barrier();
        QCOMP(QSTEPS - 1);

        #pragma unroll
        for (int f = 0; f < 2; ++f) {
            float* out = Qp + (size_t)(kz * 8192 + i0 + w * 32 + f * 16 + lg * 4) * 64 + lr;
            #pragma unroll
            for (int c = 0; c < 4; ++c) {
                #pragma unroll
                for (int j = 0; j < 4; ++j) out[j * 64 + c * 16] = acc[f][c][j];
            }
        }
        #undef QSTAGE
        #undef QCOMP
    } else {
        // ---------------- P path: rows gathered by bu, depth-4 reg pipeline
        const int pidx = bid - bid / 3 - 1;   // 0..1023
        const int gP = PKZ * 64;              // 512
        const int isS = pidx >= gP;
        int q = isS ? pidx - gP : pidx;
        int tile = q & 63, kz = q >> 6;

        int brow = tile * 64 + w * 16 + lr;
        int ridx = bu[brow];
        const float* A = (isS ? S : R) + (size_t)ridx * 8192 + kz * PKLEN + lg * 8;
        const unsigned short* Bb = (isS ? Uhb : Vhb)
                                 + (size_t)((kz * PKLEN) >> 3) * 512 + lr * 8;

        f32x4 acc[4] = {};
        f32x4 b0[4], b1[4];
        #pragma unroll
        for (int d = 0; d < 4; ++d) {
            b0[d] = ((const f32x4*)(A + d * 32))[0];
            b1[d] = ((const f32x4*)(A + d * 32))[1];
        }

        #pragma unroll 4
        for (int ks = 0; ks < PKITERS - 4; ++ks) {
            const int slot = ks & 3;
            union { bf16x8 v; unsigned u[4]; } af;
            af.u[0] = cvt_pk_bf16(b0[slot].x, b0[slot].y);
            af.u[1] = cvt_pk_bf16(b0[slot].z, b0[slot].w);
            af.u[2] = cvt_pk_bf16(b1[slot].x, b1[slot].y);
            af.u[3] = cvt_pk_bf16(b1[slot].z, b1[slot].w);
            b0[slot] = ((const f32x4*)(A + (ks + 4) * 32))[0];
            b1[slot] = ((const f32x4*)(A + (ks + 4) * 32))[1];
            const unsigned short* bp = Bb + (size_t)(ks * 4 + lg) * 512;
            #pragma unroll
            for (int c = 0; c < 4; ++c) {
                bf16x8 bf = *(const bf16x8*)(bp + c * 128);
                acc[c] = __builtin_amdgcn_mfma_f32_16x16x32_bf16(af.v, bf, acc[c], 0, 0, 0);
            }
        }
        #pragma unroll
        for (int ks = PKITERS - 4; ks < PKITERS; ++ks) {
            const int slot = ks & 3;
            union { bf16x8 v; unsigned u[4]; } af;
            af.u[0] = cvt_pk_bf16(b0[slot].x, b0[slot].y);
            af.u[1] = cvt_pk_bf16(b0[slot].z, b0[slot].w);
            af.u[2] = cvt_pk_bf16(b1[slot].x, b1[slot].y);
            af.u[3] = cvt_pk_bf16(b1[slot].z, b1[slot].w);
            const unsigned short* bp = Bb + (size_t)(ks * 4 + lg) * 512;
            #pragma unroll
            for (int c = 0; c < 4; ++c) {
                bf16x8 bf = *(const bf16x8*)(bp + c * 128);
                acc[c] = __builtin_amdgcn_mfma_f32_16x16x32_bf16(af.v, bf, acc[c], 0, 0, 0);
            }
        }

        float* out = (isS ? PpS : PpI)
                   + (size_t)(kz * 4096 + tile * 64 + w * 16 + lg * 4) * 64 + lr;
        #pragma unroll
        for (int c = 0; c < 4; ++c) {
            #pragma unroll
            for (int j = 0; j < 4; ++j) out[j * 64 + c * 16] = acc[c][j];
        }
    }
}

// ------------------------------------------------------- S1: scores A and M
__global__ __launch_bounds__(256) void k_scoreAM(
    const int* __restrict__ bu, const int* __restrict__ bi,
    const float* __restrict__ Uh, const float* __restrict__ Vh,
    const float* __restrict__ W1A, const float* __restrict__ b1A,
    const float* __restrict__ w2A, const float* __restrict__ b2A,
    const float* __restrict__ W1M, const float* __restrict__ b1M,
    const float* __restrict__ w2M, const float* __restrict__ b2M,
    float* __restrict__ sA, float* __restrict__ sM)
{
    int gt = blockIdx.x * 256 + threadIdx.x;
    int wid = gt >> 6, lane = gt & 63;
    int b0 = wid * 2;
    float ub[2], vb[2];
    #pragma unroll
    for (int j = 0; j < 2; ++j) {
        ub[j] = Uh[(size_t)bu[b0 + j] * 64 + lane];
        vb[j] = Vh[(size_t)bi[b0 + j] * 64 + lane];
    }
    float hA[2], hM[2];
    #pragma unroll
    for (int j = 0; j < 2; ++j) { hA[j] = b1A[lane]; hM[j] = b1M[lane]; }
    for (int k = 0; k < 64; ++k) {
        float wa0 = W1A[k * 64 + lane], wa1 = W1A[(64 + k) * 64 + lane];
        float wm0 = W1M[k * 64 + lane], wm1 = W1M[(64 + k) * 64 + lane];
        #pragma unroll
        for (int j = 0; j < 2; ++j) {
            float sv = __shfl(vb[j], k), su = __shfl(ub[j], k);
            hA[j] += sv * wa0 + su * wa1;   // cat(Vb, Ub)
            hM[j] += su * wm0 + sv * wm1;   // cat(Ub, Vb)
        }
    }
    float w2a = w2A[lane], w2m = w2M[lane];
    #pragma unroll
    for (int j = 0; j < 2; ++j) {
        float sa = wsum(fmaxf(hA[j], 0.f) * w2a);
        float sm = wsum(fmaxf(hM[j], 0.f) * w2m);
        if (lane == 0) { sA[b0 + j] = sa + b2A[0]; sM[b0 + j] = sm + b2M[0]; }
    }
}

// ------------------------------------------------- S2: H_I and B-scores
__global__ __launch_bounds__(256) void k_HI_scoreB(
    const float* __restrict__ PpI, const float* __restrict__ sA,
    const int* __restrict__ bu, const float* __restrict__ Uh,
    const float* __restrict__ W_I, const float* __restrict__ b_I,
    const float* __restrict__ W1B, const float* __restrict__ b1B,
    const float* __restrict__ w2B, const float* __restrict__ b2B,
    float* __restrict__ HI, float* __restrict__ sB)
{
    float m, inv;
    block_softmax_stats(sA, m, inv);
    int wid = blockIdx.x * 4 + (threadIdx.x >> 6);
    int lane = threadIdx.x & 63;
    int b0 = wid * 2;
    float p[2];
    #pragma unroll
    for (int j = 0; j < 2; ++j) {
        int b = b0 + j;
        float a = 0.f;
        #pragma unroll
        for (int kz = 0; kz < PKZ; ++kz)
            a += PpI[(size_t)(kz * 4096 + b) * 64 + lane];
        p[j] = a * (__expf(sA[b] - m) * inv);
    }
    float h[2];
    #pragma unroll
    for (int j = 0; j < 2; ++j) h[j] = b_I[lane];
    for (int k = 0; k < 64; ++k) {
        float wv = W_I[k * 64 + lane];
        #pragma unroll
        for (int j = 0; j < 2; ++j) h[j] += __shfl(p[j], k) * wv;
    }
    float ub[2];
    #pragma unroll
    for (int j = 0; j < 2; ++j) {
        h[j] = fmaxf(h[j], 0.f);
        HI[(size_t)(b0 + j) * 64 + lane] = h[j];
        ub[j] = Uh[(size_t)bu[b0 + j] * 64 + lane];
    }
    float h2[2];
    #pragma unroll
    for (int j = 0; j < 2; ++j) h2[j] = b1B[lane];
    for (int k = 0; k < 64; ++k) {
        float w0 = W1B[k * 64 + lane], w1 = W1B[(64 + k) * 64 + lane];
        #pragma unroll
        for (int j = 0; j < 2; ++j) h2[j] += __shfl(h[j], k) * w0 + __shfl(ub[j], k) * w1;
    }
    float w2 = w2B[lane];
    #pragma unroll
    for (int j = 0; j < 2; ++j) {
        float sv = wsum(fmaxf(h2[j], 0.f) * w2);
        if (lane == 0) sB[b0 + j] = sv + b2B[0];
    }
}

// ------------------------------------------------- S3: H_S then H
__global__ __launch_bounds__(256) void k_HS_H(
    const float* __restrict__ PpS, const float* __restrict__ sB,
    const float* __restrict__ HI,
    const float* __restrict__ W_Sm, const float* __restrict__ b_Sm,
    const float* __restrict__ Wc0, const float* __restrict__ bc0,
    const float* __restrict__ Wc1, const float* __restrict__ bc1,
    float* __restrict__ Hout)
{
    float m, inv;
    block_softmax_stats(sB, m, inv);
    int wid = blockIdx.x * 4 + (threadIdx.x >> 6);
    int lane = threadIdx.x & 63;
    int b0 = wid * 2;
    float p[2];
    #pragma unroll
    for (int j = 0; j < 2; ++j) {
        int b = b0 + j;
        float a = 0.f;
        #pragma unroll
        for (int kz = 0; kz < PKZ; ++kz)
            a += PpS[(size_t)(kz * 4096 + b) * 64 + lane];
        p[j] = a * (__expf(sB[b] - m) * inv);
    }
    float hs[2];
    #pragma unroll
    for (int j = 0; j < 2; ++j) hs[j] = b_Sm[lane];
    for (int k = 0; k < 64; ++k) {
        float wv = W_Sm[k * 64 + lane];
        #pragma unroll
        for (int j = 0; j < 2; ++j) hs[j] += __shfl(p[j], k) * wv;
    }
    float hi[2];
    #pragma unroll
    for (int j = 0; j < 2; ++j) {
        hs[j] = fmaxf(hs[j], 0.f);
        hi[j] = HI[(size_t)(b0 + j) * 64 + lane];
    }
    float h0[2];
    #pragma unroll
    for (int j = 0; j < 2; ++j) h0[j] = bc0[lane];
    for (int k = 0; k < 64; ++k) {
        float w0 = Wc0[k * 64 + lane], w1 = Wc0[(64 + k) * 64 + lane];
        #pragma unroll
        for (int j = 0; j < 2; ++j) h0[j] += __shfl(hi[j], k) * w0 + __shfl(hs[j], k) * w1;
    }
    #pragma unroll
    for (int j = 0; j < 2; ++j) h0[j] = fmaxf(h0[j], 0.f);
    float h1[2];
    #pragma unroll
    for (int j = 0; j < 2; ++j) h1[j] = bc1[lane];
    for (int k = 0; k < 64; ++k) {
        float wv = Wc1[k * 64 + lane];
        #pragma unroll
        for (int j = 0; j < 2; ++j) h1[j] += __shfl(h0[j], k) * wv;
    }
    #pragma unroll
    for (int j = 0; j < 2; ++j) Hout[(size_t)(b0 + j) * 64 + lane] = fmaxf(h1[j], 0.f);
}

// ------------------------------------------------- S4: Z then G (output)
__global__ __launch_bounds__(256) void k_Z_G(
    const float* __restrict__ Qp, const float* __restrict__ sM,
    const int* __restrict__ bi, const float* __restrict__ H,
    const float* __restrict__ W_Z, const float* __restrict__ b_Z,
    const float* __restrict__ Wg0, const float* __restrict__ bg0,
    const float* __restrict__ Wg1, const float* __restrict__ bg1,
    float* __restrict__ G)
{
    float m, inv;
    block_softmax_stats(sM, m, inv);
    int wid = blockIdx.x * 4 + (threadIdx.x >> 6);
    int lane = threadIdx.x & 63;
    int b0 = wid * 2;
    float p[2];
    #pragma unroll
    for (int j = 0; j < 2; ++j) {
        int b = b0 + j;
        int it = bi[b];
        float a = 0.f;
        #pragma unroll
        for (int kz = 0; kz < QKZ; ++kz)
            a += Qp[(size_t)(kz * 8192 + it) * 64 + lane];
        p[j] = a * (__expf(sM[b] - m) * inv);
    }
    float z[2];
    #pragma unroll
    for (int j = 0; j < 2; ++j) z[j] = b_Z[lane];
    for (int k = 0; k < 64; ++k) {
        float wv = W_Z[k * 64 + lane];
        #pragma unroll
        for (int j = 0; j < 2; ++j) z[j] += __shfl(p[j], k) * wv;
    }
    float hr[2];
    #pragma unroll
    for (int j = 0; j < 2; ++j) {
        z[j] = fmaxf(z[j], 0.f);
        hr[j] = H[(size_t)(b0 + j) * 64 + lane];
    }
    float g0[2];
    #pragma unroll
    for (int j = 0; j < 2; ++j) g0[j] = bg0[lane];
    for (int k = 0; k < 64; ++k) {
        float w0 = Wg0[k * 64 + lane], w1 = Wg0[(64 + k) * 64 + lane];
        #pragma unroll
        for (int j = 0; j < 2; ++j) g0[j] += __shfl(hr[j], k) * w0 + __shfl(z[j], k) * w1;
    }
    #pragma unroll
    for (int j = 0; j < 2; ++j) g0[j] = fmaxf(g0[j], 0.f);
    float g1[2];
    #pragma unroll
    for (int j = 0; j < 2; ++j) g1[j] = bg1[lane];
    for (int k = 0; k < 64; ++k) {
        float wv = Wg1[k * 64 + lane];
        #pragma unroll
        for (int j = 0; j < 2; ++j) g1[j] += __shfl(g0[j], k) * wv;
    }
    #pragma unroll
    for (int j = 0; j < 2; ++j) G[(size_t)(b0 + j) * 64 + lane] = fmaxf(g1[j], 0.f);
}

// ---------------------------------------------------------------------------
extern "C" void kernel_launch(void* const* d_in, const int* in_sizes, int n_in,
                              void* d_out, int out_size, void* d_ws, size_t ws_size,
                              hipStream_t stream)
{
    (void)in_sizes; (void)n_in; (void)out_size; (void)ws_size;
    const int*   bu  = (const int*)  d_in[0];
    const int*   bi  = (const int*)  d_in[1];
    const float* R   = (const float*)d_in[2];
    const float* S   = (const float*)d_in[3];
    const float* U   = (const float*)d_in[4];
    const float* V   = (const float*)d_in[5];
    const float* w_r = (const float*)d_in[6];
    const float* b_r = (const float*)d_in[7];
    const float* Wu0 = (const float*)d_in[8];
    const float* bu0 = (const float*)d_in[9];
    const float* Wu1 = (const float*)d_in[10];
    const float* bu1 = (const float*)d_in[11];
    const float* Wv0 = (const float*)d_in[12];
    const float* bv0 = (const float*)d_in[13];
    const float* Wv1 = (const float*)d_in[14];
    const float* bv1 = (const float*)d_in[15];
    const float* Wc0 = (const float*)d_in[16];
    const float* bc0 = (const float*)d_in[17];
    const float* Wc1 = (const float*)d_in[18];
    const float* bc1 = (const float*)d_in[19];
    const float* Wg0 = (const float*)d_in[20];
    const float* bg0 = (const float*)d_in[21];
    const float* Wg1 = (const float*)d_in[22];
    const float* bg1 = (const float*)d_in[23];
    const float* W_I = (const float*)d_in[24];
    const float* b_I = (const float*)d_in[25];
    const float* W_Sm= (const float*)d_in[26];
    const float* b_Sm= (const float*)d_in[27];
    const float* W1A = (const float*)d_in[28];
    const float* b1A = (const float*)d_in[29];
    const float* w2A = (const float*)d_in[30];
    const float* b2A = (const float*)d_in[31];
    const float* W1B = (const float*)d_in[32];
    const float* b1B = (const float*)d_in[33];
    const float* w2B = (const float*)d_in[34];
    const float* b2B = (const float*)d_in[35];
    const float* W1M = (const float*)d_in[36];
    const float* b1M = (const float*)d_in[37];
    const float* w2M = (const float*)d_in[38];
    const float* b2M = (const float*)d_in[39];
    const float* W_Z = (const float*)d_in[40];
    const float* b_Z = (const float*)d_in[41];

    char* ws = (char*)d_ws;
    size_t off = 0;
    float*          Uh  = (float*)(ws + off);          off += 2ull << 20;
    float*          Vh  = (float*)(ws + off);          off += 2ull << 20;
    unsigned short* Uhb = (unsigned short*)(ws + off); off += 1ull << 20;
    unsigned short* Vhb = (unsigned short*)(ws + off); off += 1ull << 20;
    float*          PpI = (float*)(ws + off);          off += (size_t)PKZ << 20;
    float*          PpS = (float*)(ws + off);          off += (size_t)PKZ << 20;
    float*          Qp  = (float*)(ws + off);          off += (size_t)(2 * QKZ) << 20;
    float*          sA  = (float*)(ws + off);
    float*          sM  = sA + 4096;
    float*          sB  = sA + 8192;                   off += 3 * 4096 * 4 + 4096;
    float*          HI  = (float*)(ws + off);          off += 1ull << 20;
    float*          Hh  = (float*)(ws + off);

    k_mlp<<<1024, 256, 0, stream>>>(U, V, w_r, b_r, Wu0, bu0, Wu1, bu1,
                                    Wv0, bv0, Wv1, bv1, Uh, Vh, Uhb, Vhb);
    k_gemm<<<QBLOCKS + PBLOCKS, 256, 0, stream>>>(R, S, bu, Uhb, Vhb,
                                                  PpI, PpS, Qp);
    k_scoreAM<<<512, 256, 0, stream>>>(bu, bi, Uh, Vh, W1A, b1A, w2A, b2A,
                                       W1M, b1M, w2M, b2M, sA, sM);
    k_HI_scoreB<<<512, 256, 0, stream>>>(PpI, sA, bu, Uh, W_I, b_I,
                                         W1B, b1B, w2B, b2B, HI, sB);
    k_HS_H<<<512, 256, 0, stream>>>(PpS, sB, HI, W_Sm, b_Sm, Wc0, bc0, Wc1, bc1,
                                    Hh);
    k_Z_G<<<512, 256, 0, stream>>>(Qp, sM, bi, Hh, W_Z, b_Z, Wg0, bg0, Wg1, bg1,
                                   (float*)d_out);
}

// Round 11
// 206.202 us; speedup vs baseline: 1.0167x; 1.0167x over previous
//
#include <hip/hip_runtime.h>
#include <stdint.h>

// ---------------------------------------------------------------------------
// GraphRec forward, MI355X.
//  K1 k_mlp  : e_r + 2-layer MLPs -> Uh,Vh (f32) + blocked bf16 copies
//  K2 k_gemm : merged, interleaved (bid%3==0 -> Q, else P):
//    Q: R^T@Uh. Counted-vmcnt pipeline, 3-deep 20KB LDS buffers (60KB ->
//       2 blocks/CU) holding BOTH the A tile (16KB) and B slice (4KB); in-loop
//       B reads are ds_read so the vmcnt queue stays pure staging.
//       vmcnt(10) steady state; tail vmcnt(5)/vmcnt(0).
//    P: P_I = R[bu]@Vh, P_S = S[bu]@Uh. 8 k-slabs, depth-8 f32 reg pipeline
//       (1 KB consecutive-k bytes in flight per row -> DRAM burst merge),
//       B direct from global blocked bf16 (L2-hot).
//    All f32->bf16 via v_cvt_pk_bf16_f32.
//  S1 k_scoreAM  : pre-softmax scores sA (cat(Vb,Ub)) and sM (cat(Ub,Vb))
//  S2 k_HI_scoreB: [softmax-A in-block] H_I = relu((A.P_I)@W_I+b); sB
//  S3 k_HS_H : [softmax-B] H_S = relu((B.P_S)@W_Sm+b); H = MLP(cat(H_I,H_S))
//  S4 k_Z_G  : [softmax-M] Z = relu((M.Q[bi])@W_Z+b); G = MLP(cat(H,Z))
// ---------------------------------------------------------------------------

typedef short bf16x8 __attribute__((ext_vector_type(8)));
typedef float f32x4 __attribute__((ext_vector_type(4)));

#define PKZ      8
#define PKLEN    1024        // 8192 / PKZ
#define PKITERS  32          // PKLEN / 32
#define QKZ      8
#define QSLAB    1024        // u rows per slab
#define QW       128         // i window per block
#define QSTEPS   32          // QSLAB / 32
#define QBLOCKS  512         // 64 iw x 8 kz
#define PBLOCKS  1024        // 2 * PKZ * 64

__device__ __forceinline__ unsigned cvt_pk_bf16(float lo, float hi) {
    unsigned r;
    asm("v_cvt_pk_bf16_f32 %0, %1, %2" : "=v"(r) : "v"(lo), "v"(hi));
    return r;
}

__device__ __forceinline__ float wsum(float v) {
    #pragma unroll
    for (int o = 32; o; o >>= 1) v += __shfl_xor(v, o);
    return v;
}

// block-wide softmax stats over a 4096-vector (256-thread block)
__device__ __forceinline__ void block_softmax_stats(const float* __restrict__ s,
                                                    float& m, float& inv) {
    __shared__ float r1[4];
    __shared__ float r2[4];
    int t = threadIdx.x, lane = t & 63, wv = t >> 6;
    float lm = -3.4e38f;
    #pragma unroll
    for (int i = 0; i < 16; ++i) lm = fmaxf(lm, s[t + 256 * i]);
    #pragma unroll
    for (int o = 32; o; o >>= 1) lm = fmaxf(lm, __shfl_xor(lm, o));
    if (lane == 0) r1[wv] = lm;
    __syncthreads();
    m = fmaxf(fmaxf(r1[0], r1[1]), fmaxf(r1[2], r1[3]));
    float ls = 0.f;
    #pragma unroll
    for (int i = 0; i < 16; ++i) ls += __expf(s[t + 256 * i] - m);
    ls = wsum(ls);
    if (lane == 0) r2[wv] = ls;
    __syncthreads();
    inv = 1.f / (r2[0] + r2[1] + r2[2] + r2[3]);
}

// ---------------------------------------------------------------- K1: MLPs
__global__ __launch_bounds__(256) void k_mlp(
    const float* __restrict__ U, const float* __restrict__ V,
    const float* __restrict__ w_r, const float* __restrict__ b_r,
    const float* __restrict__ Wu0, const float* __restrict__ bu0,
    const float* __restrict__ Wu1, const float* __restrict__ bu1,
    const float* __restrict__ Wv0, const float* __restrict__ bv0,
    const float* __restrict__ Wv1, const float* __restrict__ bv1,
    float* __restrict__ Uh, float* __restrict__ Vh,
    unsigned short* __restrict__ Uhb, unsigned short* __restrict__ Vhb)
{
    int gt = blockIdx.x * 256 + threadIdx.x;
    int wid = gt >> 6;
    int lane = gt & 63;

    float er = b_r[lane];
    #pragma unroll
    for (int s = 0; s < 5; ++s) er += (float)(s + 1) * w_r[s * 64 + lane];

    const int isV = (wid >= 2048);
    const float* X  = isV ? V   : U;
    const float* W0 = isV ? Wv0 : Wu0;
    const float* B0 = isV ? bv0 : bu0;
    const float* W1 = isV ? Wv1 : Wu1;
    const float* B1 = isV ? bv1 : bu1;
    float* Hout          = isV ? Vh  : Uh;
    unsigned short* Hb   = isV ? Vhb : Uhb;
    int r0 = (wid & 2047) * 4;

    float x[4];
    #pragma unroll
    for (int j = 0; j < 4; ++j) x[j] = X[(r0 + j) * 64 + lane];

    float h0c = B0[lane];
    for (int k = 0; k < 64; ++k) h0c += __shfl(er, k) * W0[(64 + k) * 64 + lane];

    float h0[4];
    #pragma unroll
    for (int j = 0; j < 4; ++j) h0[j] = h0c;
    for (int k = 0; k < 64; ++k) {
        float wv = W0[k * 64 + lane];
        #pragma unroll
        for (int j = 0; j < 4; ++j) h0[j] += __shfl(x[j], k) * wv;
    }
    #pragma unroll
    for (int j = 0; j < 4; ++j) h0[j] = fmaxf(h0[j], 0.f);

    float h1[4];
    #pragma unroll
    for (int j = 0; j < 4; ++j) h1[j] = B1[lane];
    for (int k = 0; k < 64; ++k) {
        float wv = W1[k * 64 + lane];
        #pragma unroll
        for (int j = 0; j < 4; ++j) h1[j] += __shfl(h0[j], k) * wv;
    }
    #pragma unroll
    for (int j = 0; j < 4; ++j) {
        h1[j] = fmaxf(h1[j], 0.f);
        Hout[(r0 + j) * 64 + lane] = h1[j];
    }
    // blocked bf16: element (r,d) at (r>>3)*512 + (d>>4)*128 + (d&15)*8 + (r&7)
    unsigned pw[2];
    pw[0] = cvt_pk_bf16(h1[0], h1[1]);
    pw[1] = cvt_pk_bf16(h1[2], h1[3]);
    unsigned short* dst = Hb + (size_t)(r0 >> 3) * 512 + (lane >> 4) * 128
                        + (lane & 15) * 8 + (r0 & 7);
    *(uint2*)dst = make_uint2(pw[0], pw[1]);
}

// --------------------------------------------------------------- K2: GEMMs
__global__ __launch_bounds__(256) void k_gemm(
    const float* __restrict__ R, const float* __restrict__ S,
    const int* __restrict__ bu,
    const unsigned short* __restrict__ Uhb, const unsigned short* __restrict__ Vhb,
    float* __restrict__ PpI, float* __restrict__ PpS, float* __restrict__ Qp)
{
    __shared__ alignas(16) char QLDS[3][20480];   // 60 KB: 16KB A + 4KB B per buf
    const int bid = blockIdx.x;
    const int t = threadIdx.x;
    const int w = t >> 6, l = t & 63, lg = l >> 4, lr = l & 15;

    if (bid % 3 == 0) {
        // ---------------- Q path: Q = R^T @ Uh
        const int qidx = bid / 3;          // 0..511
        const int iw = qidx & 63;
        const int kz = qidx >> 6;          // 0..7
        const int i0 = iw * QW;
        const int u0 = kz * QSLAB;

        f32x4 acc[2][4] = {};

        // stage step s into QLDS[s%3]: A tile [32u x 128i] f32 (wave w inst q
        // covers rows 2*(4q+w)..+1, 512 B contiguous each) + B slice 4 KB
        // (blocked Uhb rows u0+32s..+32, wave w stages bytes w*1024..+1024).
        #define QSTAGE(s)                                                         \
        {                                                                         \
            char* dstA = QLDS[(s) % 3];                                           \
            _Pragma("unroll")                                                     \
            for (int q = 0; q < 4; ++q) {                                         \
                const int rloc = 2 * (4 * q + w);                                 \
                const float* g = R + ((size_t)(u0 + (s) * 32 + rloc) + (l >> 5)) * 8192 \
                               + i0 + (l & 31) * 4;                               \
                __builtin_amdgcn_global_load_lds(                                 \
                    (const __attribute__((address_space(1))) void*)g,             \
                    (__attribute__((address_space(3))) void*)(dstA + rloc * 512 + l * 16), \
                    16, 0, 0);                                                    \
            }                                                                     \
            const char* bsrc = (const char*)Uhb                                   \
                + ((size_t)((u0 + (s) * 32) >> 3)) * 1024 + w * 1024 + l * 16;    \
            __builtin_amdgcn_global_load_lds(                                     \
                (const __attribute__((address_space(1))) void*)bsrc,              \
                (__attribute__((address_space(3))) void*)(dstA + 16384 + w * 1024 + l * 16), \
                16, 0, 0);                                                        \
        }

        #define QCOMP(s)                                                          \
        {                                                                         \
            const char* buf = QLDS[(s) % 3];                                      \
            const float* La = (const float*)buf;                                  \
            const short* Lbb = (const short*)(buf + 16384);                       \
            bf16x8 bfrag[4];                                                      \
            _Pragma("unroll")                                                     \
            for (int c = 0; c < 4; ++c)                                           \
                bfrag[c] = *(const bf16x8*)(Lbb + lg * 512 + c * 128 + lr * 8);   \
            _Pragma("unroll")                                                     \
            for (int f = 0; f < 2; ++f) {                                         \
                const int iloc = w * 32 + f * 16 + lr;                            \
                float av[8];                                                      \
                _Pragma("unroll")                                                 \
                for (int j = 0; j < 8; ++j) av[j] = La[(8 * lg + j) * QW + iloc]; \
                union { bf16x8 v; unsigned u[4]; } af;                            \
                _Pragma("unroll")                                                 \
                for (int qq = 0; qq < 4; ++qq)                                    \
                    af.u[qq] = cvt_pk_bf16(av[2*qq], av[2*qq+1]);                 \
                _Pragma("unroll")                                                 \
                for (int c = 0; c < 4; ++c)                                       \
                    acc[f][c] = __builtin_amdgcn_mfma_f32_16x16x32_bf16(af.v, bfrag[c], acc[f][c], 0, 0, 0); \
            }                                                                     \
        }

        QSTAGE(0); QSTAGE(1); QSTAGE(2);     // 15 insts/wave in flight

        for (int s = 0; s < QSTEPS - 2; ++s) {
            // <=10 outstanding => oldest stage (5 insts) landed
            asm volatile("s_waitcnt vmcnt(10)" ::: "memory");
            __builtin_amdgcn_s_barrier();
            QCOMP(s);
            asm volatile("s_waitcnt lgkmcnt(0)" ::: "memory");
            __builtin_amdgcn_sched_barrier(0);
            __builtin_amdgcn_s_barrier();
            if (s + 3 < QSTEPS) QSTAGE(s + 3);
        }
        asm volatile("s_waitcnt vmcnt(5)" ::: "memory");
        __builtin_amdgcn_s_barrier();
        QCOMP(QSTEPS - 2);
        asm volatile("s_waitcnt vmcnt(0)" ::: "memory");
        __builtin_amdgcn_s_barrier();
        QCOMP(QSTEPS - 1);

        #pragma unroll
        for (int f = 0; f < 2; ++f) {
            float* out = Qp + (size_t)(kz * 8192 + i0 + w * 32 + f * 16 + lg * 4) * 64 + lr;
            #pragma unroll
            for (int c = 0; c < 4; ++c) {
                #pragma unroll
                for (int j = 0; j < 4; ++j) out[j * 64 + c * 16] = acc[f][c][j];
            }
        }
        #undef QSTAGE
        #undef QCOMP
    } else {
        // ------------- P path: rows gathered by bu, depth-8 reg pipeline
        const int pidx = bid - bid / 3 - 1;   // 0..1023
        const int gP = PKZ * 64;              // 512
        const int isS = pidx >= gP;
        int q = isS ? pidx - gP : pidx;
        int tile = q & 63, kz = q >> 6;

        int brow = tile * 64 + w * 16 + lr;
        int ridx = bu[brow];
        const float* A = (isS ? S : R) + (size_t)ridx * 8192 + kz * PKLEN + lg * 8;
        const unsigned short* Bb = (isS ? Uhb : Vhb)
                                 + (size_t)((kz * PKLEN) >> 3) * 512 + lr * 8;

        f32x4 acc[4] = {};
        f32x4 b0[8], b1[8];
        #pragma unroll
        for (int d = 0; d < 8; ++d) {
            b0[d] = ((const f32x4*)(A + d * 32))[0];
            b1[d] = ((const f32x4*)(A + d * 32))[1];
        }

        #pragma unroll 8
        for (int ks = 0; ks < PKITERS - 8; ++ks) {
            const int slot = ks & 7;
            union { bf16x8 v; unsigned u[4]; } af;
            af.u[0] = cvt_pk_bf16(b0[slot].x, b0[slot].y);
            af.u[1] = cvt_pk_bf16(b0[slot].z, b0[slot].w);
            af.u[2] = cvt_pk_bf16(b1[slot].x, b1[slot].y);
            af.u[3] = cvt_pk_bf16(b1[slot].z, b1[slot].w);
            b0[slot] = ((const f32x4*)(A + (ks + 8) * 32))[0];
            b1[slot] = ((const f32x4*)(A + (ks + 8) * 32))[1];
            const unsigned short* bp = Bb + (size_t)(ks * 4 + lg) * 512;
            #pragma unroll
            for (int c = 0; c < 4; ++c) {
                bf16x8 bf = *(const bf16x8*)(bp + c * 128);
                acc[c] = __builtin_amdgcn_mfma_f32_16x16x32_bf16(af.v, bf, acc[c], 0, 0, 0);
            }
        }
        #pragma unroll
        for (int ks = PKITERS - 8; ks < PKITERS; ++ks) {
            const int slot = ks & 7;
            union { bf16x8 v; unsigned u[4]; } af;
            af.u[0] = cvt_pk_bf16(b0[slot].x, b0[slot].y);
            af.u[1] = cvt_pk_bf16(b0[slot].z, b0[slot].w);
            af.u[2] = cvt_pk_bf16(b1[slot].x, b1[slot].y);
            af.u[3] = cvt_pk_bf16(b1[slot].z, b1[slot].w);
            const unsigned short* bp = Bb + (size_t)(ks * 4 + lg) * 512;
            #pragma unroll
            for (int c = 0; c < 4; ++c) {
                bf16x8 bf = *(const bf16x8*)(bp + c * 128);
                acc[c] = __builtin_amdgcn_mfma_f32_16x16x32_bf16(af.v, bf, acc[c], 0, 0, 0);
            }
        }

        float* out = (isS ? PpS : PpI)
                   + (size_t)(kz * 4096 + tile * 64 + w * 16 + lg * 4) * 64 + lr;
        #pragma unroll
        for (int c = 0; c < 4; ++c) {
            #pragma unroll
            for (int j = 0; j < 4; ++j) out[j * 64 + c * 16] = acc[c][j];
        }
    }
}

// ------------------------------------------------------- S1: scores A and M
__global__ __launch_bounds__(256) void k_scoreAM(
    const int* __restrict__ bu, const int* __restrict__ bi,
    const float* __restrict__ Uh, const float* __restrict__ Vh,
    const float* __restrict__ W1A, const float* __restrict__ b1A,
    const float* __restrict__ w2A, const float* __restrict__ b2A,
    const float* __restrict__ W1M, const float* __restrict__ b1M,
    const float* __restrict__ w2M, const float* __restrict__ b2M,
    float* __restrict__ sA, float* __restrict__ sM)
{
    int gt = blockIdx.x * 256 + threadIdx.x;
    int wid = gt >> 6, lane = gt & 63;
    int b0 = wid * 2;
    float ub[2], vb[2];
    #pragma unroll
    for (int j = 0; j < 2; ++j) {
        ub[j] = Uh[(size_t)bu[b0 + j] * 64 + lane];
        vb[j] = Vh[(size_t)bi[b0 + j] * 64 + lane];
    }
    float hA[2], hM[2];
    #pragma unroll
    for (int j = 0; j < 2; ++j) { hA[j] = b1A[lane]; hM[j] = b1M[lane]; }
    for (int k = 0; k < 64; ++k) {
        float wa0 = W1A[k * 64 + lane], wa1 = W1A[(64 + k) * 64 + lane];
        float wm0 = W1M[k * 64 + lane], wm1 = W1M[(64 + k) * 64 + lane];
        #pragma unroll
        for (int j = 0; j < 2; ++j) {
            float sv = __shfl(vb[j], k), su = __shfl(ub[j], k);
            hA[j] += sv * wa0 + su * wa1;   // cat(Vb, Ub)
            hM[j] += su * wm0 + sv * wm1;   // cat(Ub, Vb)
        }
    }
    float w2a = w2A[lane], w2m = w2M[lane];
    #pragma unroll
    for (int j = 0; j < 2; ++j) {
        float sa = wsum(fmaxf(hA[j], 0.f) * w2a);
        float sm = wsum(fmaxf(hM[j], 0.f) * w2m);
        if (lane == 0) { sA[b0 + j] = sa + b2A[0]; sM[b0 + j] = sm + b2M[0]; }
    }
}

// ------------------------------------------------- S2: H_I and B-scores
__global__ __launch_bounds__(256) void k_HI_scoreB(
    const float* __restrict__ PpI, const float* __restrict__ sA,
    const int* __restrict__ bu, const float* __restrict__ Uh,
    const float* __restrict__ W_I, const float* __restrict__ b_I,
    const float* __restrict__ W1B, const float* __restrict__ b1B,
    const float* __restrict__ w2B, const float* __restrict__ b2B,
    float* __restrict__ HI, float* __restrict__ sB)
{
    float m, inv;
    block_softmax_stats(sA, m, inv);
    int wid = blockIdx.x * 4 + (threadIdx.x >> 6);
    int lane = threadIdx.x & 63;
    int b0 = wid * 2;
    float p[2];
    #pragma unroll
    for (int j = 0; j < 2; ++j) {
        int b = b0 + j;
        float a = 0.f;
        #pragma unroll
        for (int kz = 0; kz < PKZ; ++kz)
            a += PpI[(size_t)(kz * 4096 + b) * 64 + lane];
        p[j] = a * (__expf(sA[b] - m) * inv);
    }
    float h[2];
    #pragma unroll
    for (int j = 0; j < 2; ++j) h[j] = b_I[lane];
    for (int k = 0; k < 64; ++k) {
        float wv = W_I[k * 64 + lane];
        #pragma unroll
        for (int j = 0; j < 2; ++j) h[j] += __shfl(p[j], k) * wv;
    }
    float ub[2];
    #pragma unroll
    for (int j = 0; j < 2; ++j) {
        h[j] = fmaxf(h[j], 0.f);
        HI[(size_t)(b0 + j) * 64 + lane] = h[j];
        ub[j] = Uh[(size_t)bu[b0 + j] * 64 + lane];
    }
    float h2[2];
    #pragma unroll
    for (int j = 0; j < 2; ++j) h2[j] = b1B[lane];
    for (int k = 0; k < 64; ++k) {
        float w0 = W1B[k * 64 + lane], w1 = W1B[(64 + k) * 64 + lane];
        #pragma unroll
        for (int j = 0; j < 2; ++j) h2[j] += __shfl(h[j], k) * w0 + __shfl(ub[j], k) * w1;
    }
    float w2 = w2B[lane];
    #pragma unroll
    for (int j = 0; j < 2; ++j) {
        float sv = wsum(fmaxf(h2[j], 0.f) * w2);
        if (lane == 0) sB[b0 + j] = sv + b2B[0];
    }
}

// ------------------------------------------------- S3: H_S then H
__global__ __launch_bounds__(256) void k_HS_H(
    const float* __restrict__ PpS, const float* __restrict__ sB,
    const float* __restrict__ HI,
    const float* __restrict__ W_Sm, const float* __restrict__ b_Sm,
    const float* __restrict__ Wc0, const float* __restrict__ bc0,
    const float* __restrict__ Wc1, const float* __restrict__ bc1,
    float* __restrict__ Hout)
{
    float m, inv;
    block_softmax_stats(sB, m, inv);
    int wid = blockIdx.x * 4 + (threadIdx.x >> 6);
    int lane = threadIdx.x & 63;
    int b0 = wid * 2;
    float p[2];
    #pragma unroll
    for (int j = 0; j < 2; ++j) {
        int b = b0 + j;
        float a = 0.f;
        #pragma unroll
        for (int kz = 0; kz < PKZ; ++kz)
            a += PpS[(size_t)(kz * 4096 + b) * 64 + lane];
        p[j] = a * (__expf(sB[b] - m) * inv);
    }
    float hs[2];
    #pragma unroll
    for (int j = 0; j < 2; ++j) hs[j] = b_Sm[lane];
    for (int k = 0; k < 64; ++k) {
        float wv = W_Sm[k * 64 + lane];
        #pragma unroll
        for (int j = 0; j < 2; ++j) hs[j] += __shfl(p[j], k) * wv;
    }
    float hi[2];
    #pragma unroll
    for (int j = 0; j < 2; ++j) {
        hs[j] = fmaxf(hs[j], 0.f);
        hi[j] = HI[(size_t)(b0 + j) * 64 + lane];
    }
    float h0[2];
    #pragma unroll
    for (int j = 0; j < 2; ++j) h0[j] = bc0[lane];
    for (int k = 0; k < 64; ++k) {
        float w0 = Wc0[k * 64 + lane], w1 = Wc0[(64 + k) * 64 + lane];
        #pragma unroll
        for (int j = 0; j < 2; ++j) h0[j] += __shfl(hi[j], k) * w0 + __shfl(hs[j], k) * w1;
    }
    #pragma unroll
    for (int j = 0; j < 2; ++j) h0[j] = fmaxf(h0[j], 0.f);
    float h1[2];
    #pragma unroll
    for (int j = 0; j < 2; ++j) h1[j] = bc1[lane];
    for (int k = 0; k < 64; ++k) {
        float wv = Wc1[k * 64 + lane];
        #pragma unroll
        for (int j = 0; j < 2; ++j) h1[j] += __shfl(h0[j], k) * wv;
    }
    #pragma unroll
    for (int j = 0; j < 2; ++j) Hout[(size_t)(b0 + j) * 64 + lane] = fmaxf(h1[j], 0.f);
}

// ------------------------------------------------- S4: Z then G (output)
__global__ __launch_bounds__(256) void k_Z_G(
    const float* __restrict__ Qp, const float* __restrict__ sM,
    const int* __restrict__ bi, const float* __restrict__ H,
    const float* __restrict__ W_Z, const float* __restrict__ b_Z,
    const float* __restrict__ Wg0, const float* __restrict__ bg0,
    const float* __restrict__ Wg1, const float* __restrict__ bg1,
    float* __restrict__ G)
{
    float m, inv;
    block_softmax_stats(sM, m, inv);
    int wid = blockIdx.x * 4 + (threadIdx.x >> 6);
    int lane = threadIdx.x & 63;
    int b0 = wid * 2;
    float p[2];
    #pragma unroll
    for (int j = 0; j < 2; ++j) {
        int b = b0 + j;
        int it = bi[b];
        float a = 0.f;
        #pragma unroll
        for (int kz = 0; kz < QKZ; ++kz)
            a += Qp[(size_t)(kz * 8192 + it) * 64 + lane];
        p[j] = a * (__expf(sM[b] - m) * inv);
    }
    float z[2];
    #pragma unroll
    for (int j = 0; j < 2; ++j) z[j] = b_Z[lane];
    for (int k = 0; k < 64; ++k) {
        float wv = W_Z[k * 64 + lane];
        #pragma unroll
        for (int j = 0; j < 2; ++j) z[j] += __shfl(p[j], k) * wv;
    }
    float hr[2];
    #pragma unroll
    for (int j = 0; j < 2; ++j) {
        z[j] = fmaxf(z[j], 0.f);
        hr[j] = H[(size_t)(b0 + j) * 64 + lane];
    }
    float g0[2];
    #pragma unroll
    for (int j = 0; j < 2; ++j) g0[j] = bg0[lane];
    for (int k = 0; k < 64; ++k) {
        float w0 = Wg0[k * 64 + lane], w1 = Wg0[(64 + k) * 64 + lane];
        #pragma unroll
        for (int j = 0; j < 2; ++j) g0[j] += __shfl(hr[j], k) * w0 + __shfl(z[j], k) * w1;
    }
    #pragma unroll
    for (int j = 0; j < 2; ++j) g0[j] = fmaxf(g0[j], 0.f);
    float g1[2];
    #pragma unroll
    for (int j = 0; j < 2; ++j) g1[j] = bg1[lane];
    for (int k = 0; k < 64; ++k) {
        float wv = Wg1[k * 64 + lane];
        #pragma unroll
        for (int j = 0; j < 2; ++j) g1[j] += __shfl(g0[j], k) * wv;
    }
    #pragma unroll
    for (int j = 0; j < 2; ++j) G[(size_t)(b0 + j) * 64 + lane] = fmaxf(g1[j], 0.f);
}

// ---------------------------------------------------------------------------
extern "C" void kernel_launch(void* const* d_in, const int* in_sizes, int n_in,
                              void* d_out, int out_size, void* d_ws, size_t ws_size,
                              hipStream_t stream)
{
    (void)in_sizes; (void)n_in; (void)out_size; (void)ws_size;
    const int*   bu  = (const int*)  d_in[0];
    const int*   bi  = (const int*)  d_in[1];
    const float* R   = (const float*)d_in[2];
    const float* S   = (const float*)d_in[3];
    const float* U   = (const float*)d_in[4];
    const float* V   = (const float*)d_in[5];
    const float* w_r = (const float*)d_in[6];
    const float* b_r = (const float*)d_in[7];
    const float* Wu0 = (const float*)d_in[8];
    const float* bu0 = (const float*)d_in[9];
    const float* Wu1 = (const float*)d_in[10];
    const float* bu1 = (const float*)d_in[11];
    const float* Wv0 = (const float*)d_in[12];
    const float* bv0 = (const float*)d_in[13];
    const float* Wv1 = (const float*)d_in[14];
    const float* bv1 = (const float*)d_in[15];
    const float* Wc0 = (const float*)d_in[16];
    const float* bc0 = (const float*)d_in[17];
    const float* Wc1 = (const float*)d_in[18];
    const float* bc1 = (const float*)d_in[19];
    const float* Wg0 = (const float*)d_in[20];
    const float* bg0 = (const float*)d_in[21];
    const float* Wg1 = (const float*)d_in[22];
    const float* bg1 = (const float*)d_in[23];
    const float* W_I = (const float*)d_in[24];
    const float* b_I = (const float*)d_in[25];
    const float* W_Sm= (const float*)d_in[26];
    const float* b_Sm= (const float*)d_in[27];
    const float* W1A = (const float*)d_in[28];
    const float* b1A = (const float*)d_in[29];
    const float* w2A = (const float*)d_in[30];
    const float* b2A = (const float*)d_in[31];
    const float* W1B = (const float*)d_in[32];
    const float* b1B = (const float*)d_in[33];
    const float* w2B = (const float*)d_in[34];
    const float* b2B = (const float*)d_in[35];
    const float* W1M = (const float*)d_in[36];
    const float* b1M = (const float*)d_in[37];
    const float* w2M = (const float*)d_in[38];
    const float* b2M = (const float*)d_in[39];
    const float* W_Z = (const float*)d_in[40];
    const float* b_Z = (const float*)d_in[41];

    char* ws = (char*)d_ws;
    size_t off = 0;
    float*          Uh  = (float*)(ws + off);          off += 2ull << 20;
    float*          Vh  = (float*)(ws + off);          off += 2ull << 20;
    unsigned short* Uhb = (unsigned short*)(ws + off); off += 1ull << 20;
    unsigned short* Vhb = (unsigned short*)(ws + off); off += 1ull << 20;
    float*          PpI = (float*)(ws + off);          off += (size_t)PKZ << 20;
    float*          PpS = (float*)(ws + off);          off += (size_t)PKZ << 20;
    float*          Qp  = (float*)(ws + off);          off += (size_t)(2 * QKZ) << 20;
    float*          sA  = (float*)(ws + off);
    float*          sM  = sA + 4096;
    float*          sB  = sA + 8192;                   off += 3 * 4096 * 4 + 4096;
    float*          HI  = (float*)(ws + off);          off += 1ull << 20;
    float*          Hh  = (float*)(ws + off);

    k_mlp<<<1024, 256, 0, stream>>>(U, V, w_r, b_r, Wu0, bu0, Wu1, bu1,
                                    Wv0, bv0, Wv1, bv1, Uh, Vh, Uhb, Vhb);
    k_gemm<<<QBLOCKS + PBLOCKS, 256, 0, stream>>>(R, S, bu, Uhb, Vhb,
                                                  PpI, PpS, Qp);
    k_scoreAM<<<512, 256, 0, stream>>>(bu, bi, Uh, Vh, W1A, b1A, w2A, b2A,
                                       W1M, b1M, w2M, b2M, sA, sM);
    k_HI_scoreB<<<512, 256, 0, stream>>>(PpI, sA, bu, Uh, W_I, b_I,
                                         W1B, b1B, w2B, b2B, HI, sB);
    k_HS_H<<<512, 256, 0, stream>>>(PpS, sB, HI, W_Sm, b_Sm, Wc0, bc0, Wc1, bc1,
                                    Hh);
    k_Z_G<<<512, 256, 0, stream>>>(Qp, sM, bi, Hh, W_Z, b_Z, Wg0, bg0, Wg1, bg1,
                                   (float*)d_out);
}

// Round 12
// 193.461 us; speedup vs baseline: 1.0836x; 1.0659x over previous
//
#include <hip/hip_runtime.h>
#include <stdint.h>

// ---------------------------------------------------------------------------
// GraphRec forward, MI355X.
//  K1 k_mlp  : e_r + 2-layer MLPs -> Uh,Vh (f32) + blocked bf16 copies
//  K2 k_gemm : merged dispatch, 3 block roles:
//    bid in [0,1536), bid%3==0 -> Q: R^T@Uh. Counted-vmcnt pipeline, 3-deep
//       20KB LDS buffers (A 16KB + B 4KB); in-loop B reads are ds_read so the
//       vmcnt queue stays pure staging. vmcnt(10) steady / 5 / 0 tail.
//    bid in [0,1536), bid%3!=0 -> P: P_I=R[bu]@Vh, P_S=S[bu]@Uh. 8 k-slabs,
//       depth-4 f32 reg pipeline, B direct from global blocked bf16 (L2-hot).
//    bid in [1536,2048) -> scoreAM: pre-softmax scores sA/sM (needs only
//       Uh/Vh, ready before this dispatch; outputs consumed two launches later)
//  S2 k_HI_scoreB: [softmax-A in-block] H_I = relu((A.P_I)@W_I+b); sB
//  S3 k_HS_H : [softmax-B] H_S = relu((B.P_S)@W_Sm+b); H = MLP(cat(H_I,H_S))
//  S4 k_Z_G  : [softmax-M] Z = relu((M.Q[bi])@W_Z+b); G = MLP(cat(H,Z))
// ---------------------------------------------------------------------------

typedef short bf16x8 __attribute__((ext_vector_type(8)));
typedef float f32x4 __attribute__((ext_vector_type(4)));

#define PKZ      8
#define PKLEN    1024        // 8192 / PKZ
#define PKITERS  32          // PKLEN / 32
#define QKZ      8
#define QSLAB    1024        // u rows per slab
#define QW       128         // i window per block
#define QSTEPS   32          // QSLAB / 32
#define QBLOCKS  512         // 64 iw x 8 kz
#define PBLOCKS  1024        // 2 * PKZ * 64
#define SBLOCKS  512         // scoreAM blocks

__device__ __forceinline__ unsigned f2bf1(float f) {
    unsigned x = __float_as_uint(f);
    return (x + 0x7FFFu + ((x >> 16) & 1u)) >> 16;   // RNE f32->bf16
}

__device__ __forceinline__ float wsum(float v) {
    #pragma unroll
    for (int o = 32; o; o >>= 1) v += __shfl_xor(v, o);
    return v;
}

// block-wide softmax stats over a 4096-vector (256-thread block)
__device__ __forceinline__ void block_softmax_stats(const float* __restrict__ s,
                                                    float& m, float& inv) {
    __shared__ float r1[4];
    __shared__ float r2[4];
    int t = threadIdx.x, lane = t & 63, wv = t >> 6;
    float lm = -3.4e38f;
    #pragma unroll
    for (int i = 0; i < 16; ++i) lm = fmaxf(lm, s[t + 256 * i]);
    #pragma unroll
    for (int o = 32; o; o >>= 1) lm = fmaxf(lm, __shfl_xor(lm, o));
    if (lane == 0) r1[wv] = lm;
    __syncthreads();
    m = fmaxf(fmaxf(r1[0], r1[1]), fmaxf(r1[2], r1[3]));
    float ls = 0.f;
    #pragma unroll
    for (int i = 0; i < 16; ++i) ls += __expf(s[t + 256 * i] - m);
    ls = wsum(ls);
    if (lane == 0) r2[wv] = ls;
    __syncthreads();
    inv = 1.f / (r2[0] + r2[1] + r2[2] + r2[3]);
}

// ---------------------------------------------------------------- K1: MLPs
__global__ __launch_bounds__(256) void k_mlp(
    const float* __restrict__ U, const float* __restrict__ V,
    const float* __restrict__ w_r, const float* __restrict__ b_r,
    const float* __restrict__ Wu0, const float* __restrict__ bu0,
    const float* __restrict__ Wu1, const float* __restrict__ bu1,
    const float* __restrict__ Wv0, const float* __restrict__ bv0,
    const float* __restrict__ Wv1, const float* __restrict__ bv1,
    float* __restrict__ Uh, float* __restrict__ Vh,
    unsigned short* __restrict__ Uhb, unsigned short* __restrict__ Vhb)
{
    int gt = blockIdx.x * 256 + threadIdx.x;
    int wid = gt >> 6;
    int lane = gt & 63;

    float er = b_r[lane];
    #pragma unroll
    for (int s = 0; s < 5; ++s) er += (float)(s + 1) * w_r[s * 64 + lane];

    const int isV = (wid >= 2048);
    const float* X  = isV ? V   : U;
    const float* W0 = isV ? Wv0 : Wu0;
    const float* B0 = isV ? bv0 : bu0;
    const float* W1 = isV ? Wv1 : Wu1;
    const float* B1 = isV ? bv1 : bu1;
    float* Hout          = isV ? Vh  : Uh;
    unsigned short* Hb   = isV ? Vhb : Uhb;
    int r0 = (wid & 2047) * 4;

    float x[4];
    #pragma unroll
    for (int j = 0; j < 4; ++j) x[j] = X[(r0 + j) * 64 + lane];

    float h0c = B0[lane];
    for (int k = 0; k < 64; ++k) h0c += __shfl(er, k) * W0[(64 + k) * 64 + lane];

    float h0[4];
    #pragma unroll
    for (int j = 0; j < 4; ++j) h0[j] = h0c;
    for (int k = 0; k < 64; ++k) {
        float wv = W0[k * 64 + lane];
        #pragma unroll
        for (int j = 0; j < 4; ++j) h0[j] += __shfl(x[j], k) * wv;
    }
    #pragma unroll
    for (int j = 0; j < 4; ++j) h0[j] = fmaxf(h0[j], 0.f);

    float h1[4];
    #pragma unroll
    for (int j = 0; j < 4; ++j) h1[j] = B1[lane];
    for (int k = 0; k < 64; ++k) {
        float wv = W1[k * 64 + lane];
        #pragma unroll
        for (int j = 0; j < 4; ++j) h1[j] += __shfl(h0[j], k) * wv;
    }
    #pragma unroll
    for (int j = 0; j < 4; ++j) {
        h1[j] = fmaxf(h1[j], 0.f);
        Hout[(r0 + j) * 64 + lane] = h1[j];
    }
    // blocked bf16: element (r,d) at (r>>3)*512 + (d>>4)*128 + (d&15)*8 + (r&7)
    unsigned pw[2];
    #pragma unroll
    for (int q = 0; q < 2; ++q) pw[q] = f2bf1(h1[2*q]) | (f2bf1(h1[2*q+1]) << 16);
    unsigned short* dst = Hb + (size_t)(r0 >> 3) * 512 + (lane >> 4) * 128
                        + (lane & 15) * 8 + (r0 & 7);
    *(uint2*)dst = make_uint2(pw[0], pw[1]);
}

// --------------------------------------------------------------- K2: GEMMs
__global__ __launch_bounds__(256) void k_gemm(
    const float* __restrict__ R, const float* __restrict__ S,
    const int* __restrict__ bu, const int* __restrict__ bi,
    const unsigned short* __restrict__ Uhb, const unsigned short* __restrict__ Vhb,
    const float* __restrict__ Uh, const float* __restrict__ Vh,
    const float* __restrict__ W1A, const float* __restrict__ b1A,
    const float* __restrict__ w2A, const float* __restrict__ b2A,
    const float* __restrict__ W1M, const float* __restrict__ b1M,
    const float* __restrict__ w2M, const float* __restrict__ b2M,
    float* __restrict__ PpI, float* __restrict__ PpS, float* __restrict__ Qp,
    float* __restrict__ sA, float* __restrict__ sM)
{
    __shared__ alignas(16) char QLDS[3][20480];   // 60 KB: 16KB A + 4KB B per buf
    const int bid = blockIdx.x;
    const int t = threadIdx.x;
    const int w = t >> 6, l = t & 63, lg = l >> 4, lr = l & 15;

    if (bid >= QBLOCKS + PBLOCKS) {
        // ---------------- scoreAM path: sA (cat(Vb,Ub)), sM (cat(Ub,Vb))
        int wid = (bid - QBLOCKS - PBLOCKS) * 4 + w;
        int b0 = wid * 2;
        float ub[2], vb[2];
        #pragma unroll
        for (int j = 0; j < 2; ++j) {
            ub[j] = Uh[(size_t)bu[b0 + j] * 64 + l];
            vb[j] = Vh[(size_t)bi[b0 + j] * 64 + l];
        }
        float hA[2], hM[2];
        #pragma unroll
        for (int j = 0; j < 2; ++j) { hA[j] = b1A[l]; hM[j] = b1M[l]; }
        for (int k = 0; k < 64; ++k) {
            float wa0 = W1A[k * 64 + l], wa1 = W1A[(64 + k) * 64 + l];
            float wm0 = W1M[k * 64 + l], wm1 = W1M[(64 + k) * 64 + l];
            #pragma unroll
            for (int j = 0; j < 2; ++j) {
                float sv = __shfl(vb[j], k), su = __shfl(ub[j], k);
                hA[j] += sv * wa0 + su * wa1;   // cat(Vb, Ub)
                hM[j] += su * wm0 + sv * wm1;   // cat(Ub, Vb)
            }
        }
        float w2a = w2A[l], w2m = w2M[l];
        #pragma unroll
        for (int j = 0; j < 2; ++j) {
            float sa = wsum(fmaxf(hA[j], 0.f) * w2a);
            float sm = wsum(fmaxf(hM[j], 0.f) * w2m);
            if (l == 0) { sA[b0 + j] = sa + b2A[0]; sM[b0 + j] = sm + b2M[0]; }
        }
        return;
    }

    if (bid % 3 == 0) {
        // ---------------- Q path: Q = R^T @ Uh
        const int qidx = bid / 3;          // 0..511
        const int iw = qidx & 63;
        const int kz = qidx >> 6;          // 0..7
        const int i0 = iw * QW;
        const int u0 = kz * QSLAB;

        f32x4 acc[2][4] = {};

        // stage step s into QLDS[s%3]: A tile [32u x 128i] f32 (wave w inst q
        // covers rows 2*(4q+w)..+1, 512 B contiguous each) + B slice 4 KB
        // (blocked Uhb rows u0+32s..+32, wave w stages bytes w*1024..+1024).
        #define QSTAGE(s)                                                         \
        {                                                                         \
            char* dstA = QLDS[(s) % 3];                                           \
            _Pragma("unroll")                                                     \
            for (int q = 0; q < 4; ++q) {                                         \
                const int rloc = 2 * (4 * q + w);                                 \
                const float* g = R + ((size_t)(u0 + (s) * 32 + rloc) + (l >> 5)) * 8192 \
                               + i0 + (l & 31) * 4;                               \
                __builtin_amdgcn_global_load_lds(                                 \
                    (const __attribute__((address_space(1))) void*)g,             \
                    (__attribute__((address_space(3))) void*)(dstA + rloc * 512 + l * 16), \
                    16, 0, 0);                                                    \
            }                                                                     \
            const char* bsrc = (const char*)Uhb                                   \
                + ((size_t)((u0 + (s) * 32) >> 3)) * 1024 + w * 1024 + l * 16;    \
            __builtin_amdgcn_global_load_lds(                                     \
                (const __attribute__((address_space(1))) void*)bsrc,              \
                (__attribute__((address_space(3))) void*)(dstA + 16384 + w * 1024 + l * 16), \
                16, 0, 0);                                                        \
        }

        #define QCOMP(s)                                                          \
        {                                                                         \
            const char* buf = QLDS[(s) % 3];                                      \
            const float* La = (const float*)buf;                                  \
            const short* Lbb = (const short*)(buf + 16384);                       \
            bf16x8 bfrag[4];                                                      \
            _Pragma("unroll")                                                     \
            for (int c = 0; c < 4; ++c)                                           \
                bfrag[c] = *(const bf16x8*)(Lbb + lg * 512 + c * 128 + lr * 8);   \
            _Pragma("unroll")                                                     \
            for (int f = 0; f < 2; ++f) {                                         \
                const int iloc = w * 32 + f * 16 + lr;                            \
                float av[8];                                                      \
                _Pragma("unroll")                                                 \
                for (int j = 0; j < 8; ++j) av[j] = La[(8 * lg + j) * QW + iloc]; \
                union { bf16x8 v; unsigned u[4]; } af;                            \
                _Pragma("unroll")                                                 \
                for (int qq = 0; qq < 4; ++qq)                                    \
                    af.u[qq] = f2bf1(av[2*qq]) | (f2bf1(av[2*qq+1]) << 16);       \
                _Pragma("unroll")                                                 \
                for (int c = 0; c < 4; ++c)                                       \
                    acc[f][c] = __builtin_amdgcn_mfma_f32_16x16x32_bf16(af.v, bfrag[c], acc[f][c], 0, 0, 0); \
            }                                                                     \
        }

        QSTAGE(0); QSTAGE(1); QSTAGE(2);     // 15 insts/wave in flight

        for (int s = 0; s < QSTEPS - 2; ++s) {
            // <=10 outstanding => oldest stage (5 insts) landed
            asm volatile("s_waitcnt vmcnt(10)" ::: "memory");
            __builtin_amdgcn_s_barrier();
            QCOMP(s);
            asm volatile("s_waitcnt lgkmcnt(0)" ::: "memory");
            __builtin_amdgcn_sched_barrier(0);
            __builtin_amdgcn_s_barrier();
            if (s + 3 < QSTEPS) QSTAGE(s + 3);
        }
        asm volatile("s_waitcnt vmcnt(5)" ::: "memory");
        __builtin_amdgcn_s_barrier();
        QCOMP(QSTEPS - 2);
        asm volatile("s_waitcnt vmcnt(0)" ::: "memory");
        __builtin_amdgcn_s_barrier();
        QCOMP(QSTEPS - 1);

        #pragma unroll
        for (int f = 0; f < 2; ++f) {
            float* out = Qp + (size_t)(kz * 8192 + i0 + w * 32 + f * 16 + lg * 4) * 64 + lr;
            #pragma unroll
            for (int c = 0; c < 4; ++c) {
                #pragma unroll
                for (int j = 0; j < 4; ++j) out[j * 64 + c * 16] = acc[f][c][j];
            }
        }
        #undef QSTAGE
        #undef QCOMP
    } else {
        // ------------- P path: rows gathered by bu, depth-4 reg pipeline
        const int pidx = bid - bid / 3 - 1;   // 0..1023
        const int gP = PKZ * 64;              // 512
        const int isS = pidx >= gP;
        int q = isS ? pidx - gP : pidx;
        int tile = q & 63, kz = q >> 6;

        int brow = tile * 64 + w * 16 + lr;
        int ridx = bu[brow];
        const float* A = (isS ? S : R) + (size_t)ridx * 8192 + kz * PKLEN + lg * 8;
        const unsigned short* Bb = (isS ? Uhb : Vhb)
                                 + (size_t)((kz * PKLEN) >> 3) * 512 + lr * 8;

        f32x4 acc[4] = {};
        f32x4 b0[4], b1[4];
        #pragma unroll
        for (int d = 0; d < 4; ++d) {
            b0[d] = ((const f32x4*)(A + d * 32))[0];
            b1[d] = ((const f32x4*)(A + d * 32))[1];
        }

        #pragma unroll 4
        for (int ks = 0; ks < PKITERS - 4; ++ks) {
            const int slot = ks & 3;
            union { bf16x8 v; unsigned u[4]; } af;
            af.u[0] = f2bf1(b0[slot].x) | (f2bf1(b0[slot].y) << 16);
            af.u[1] = f2bf1(b0[slot].z) | (f2bf1(b0[slot].w) << 16);
            af.u[2] = f2bf1(b1[slot].x) | (f2bf1(b1[slot].y) << 16);
            af.u[3] = f2bf1(b1[slot].z) | (f2bf1(b1[slot].w) << 16);
            b0[slot] = ((const f32x4*)(A + (ks + 4) * 32))[0];
            b1[slot] = ((const f32x4*)(A + (ks + 4) * 32))[1];
            const unsigned short* bp = Bb + (size_t)(ks * 4 + lg) * 512;
            #pragma unroll
            for (int c = 0; c < 4; ++c) {
                bf16x8 bf = *(const bf16x8*)(bp + c * 128);
                acc[c] = __builtin_amdgcn_mfma_f32_16x16x32_bf16(af.v, bf, acc[c], 0, 0, 0);
            }
        }
        #pragma unroll
        for (int ks = PKITERS - 4; ks < PKITERS; ++ks) {
            const int slot = ks & 3;
            union { bf16x8 v; unsigned u[4]; } af;
            af.u[0] = f2bf1(b0[slot].x) | (f2bf1(b0[slot].y) << 16);
            af.u[1] = f2bf1(b0[slot].z) | (f2bf1(b0[slot].w) << 16);
            af.u[2] = f2bf1(b1[slot].x) | (f2bf1(b1[slot].y) << 16);
            af.u[3] = f2bf1(b1[slot].z) | (f2bf1(b1[slot].w) << 16);
            const unsigned short* bp = Bb + (size_t)(ks * 4 + lg) * 512;
            #pragma unroll
            for (int c = 0; c < 4; ++c) {
                bf16x8 bf = *(const bf16x8*)(bp + c * 128);
                acc[c] = __builtin_amdgcn_mfma_f32_16x16x32_bf16(af.v, bf, acc[c], 0, 0, 0);
            }
        }

        float* out = (isS ? PpS : PpI)
                   + (size_t)(kz * 4096 + tile * 64 + w * 16 + lg * 4) * 64 + lr;
        #pragma unroll
        for (int c = 0; c < 4; ++c) {
            #pragma unroll
            for (int j = 0; j < 4; ++j) out[j * 64 + c * 16] = acc[c][j];
        }
    }
}

// ------------------------------------------------- S2: H_I and B-scores
__global__ __launch_bounds__(256) void k_HI_scoreB(
    const float* __restrict__ PpI, const float* __restrict__ sA,
    const int* __restrict__ bu, const float* __restrict__ Uh,
    const float* __restrict__ W_I, const float* __restrict__ b_I,
    const float* __restrict__ W1B, const float* __restrict__ b1B,
    const float* __restrict__ w2B, const float* __restrict__ b2B,
    float* __restrict__ HI, float* __restrict__ sB)
{
    float m, inv;
    block_softmax_stats(sA, m, inv);
    int wid = blockIdx.x * 4 + (threadIdx.x >> 6);
    int lane = threadIdx.x & 63;
    int b0 = wid * 2;
    float p[2];
    #pragma unroll
    for (int j = 0; j < 2; ++j) {
        int b = b0 + j;
        float a = 0.f;
        #pragma unroll
        for (int kz = 0; kz < PKZ; ++kz)
            a += PpI[(size_t)(kz * 4096 + b) * 64 + lane];
        p[j] = a * (__expf(sA[b] - m) * inv);
    }
    float h[2];
    #pragma unroll
    for (int j = 0; j < 2; ++j) h[j] = b_I[lane];
    for (int k = 0; k < 64; ++k) {
        float wv = W_I[k * 64 + lane];
        #pragma unroll
        for (int j = 0; j < 2; ++j) h[j] += __shfl(p[j], k) * wv;
    }
    float ub[2];
    #pragma unroll
    for (int j = 0; j < 2; ++j) {
        h[j] = fmaxf(h[j], 0.f);
        HI[(size_t)(b0 + j) * 64 + lane] = h[j];
        ub[j] = Uh[(size_t)bu[b0 + j] * 64 + lane];
    }
    float h2[2];
    #pragma unroll
    for (int j = 0; j < 2; ++j) h2[j] = b1B[lane];
    for (int k = 0; k < 64; ++k) {
        float w0 = W1B[k * 64 + lane], w1 = W1B[(64 + k) * 64 + lane];
        #pragma unroll
        for (int j = 0; j < 2; ++j) h2[j] += __shfl(h[j], k) * w0 + __shfl(ub[j], k) * w1;
    }
    float w2 = w2B[lane];
    #pragma unroll
    for (int j = 0; j < 2; ++j) {
        float sv = wsum(fmaxf(h2[j], 0.f) * w2);
        if (lane == 0) sB[b0 + j] = sv + b2B[0];
    }
}

// ------------------------------------------------- S3: H_S then H
__global__ __launch_bounds__(256) void k_HS_H(
    const float* __restrict__ PpS, const float* __restrict__ sB,
    const float* __restrict__ HI,
    const float* __restrict__ W_Sm, const float* __restrict__ b_Sm,
    const float* __restrict__ Wc0, const float* __restrict__ bc0,
    const float* __restrict__ Wc1, const float* __restrict__ bc1,
    float* __restrict__ Hout)
{
    float m, inv;
    block_softmax_stats(sB, m, inv);
    int wid = blockIdx.x * 4 + (threadIdx.x >> 6);
    int lane = threadIdx.x & 63;
    int b0 = wid * 2;
    float p[2];
    #pragma unroll
    for (int j = 0; j < 2; ++j) {
        int b = b0 + j;
        float a = 0.f;
        #pragma unroll
        for (int kz = 0; kz < PKZ; ++kz)
            a += PpS[(size_t)(kz * 4096 + b) * 64 + lane];
        p[j] = a * (__expf(sB[b] - m) * inv);
    }
    float hs[2];
    #pragma unroll
    for (int j = 0; j < 2; ++j) hs[j] = b_Sm[lane];
    for (int k = 0; k < 64; ++k) {
        float wv = W_Sm[k * 64 + lane];
        #pragma unroll
        for (int j = 0; j < 2; ++j) hs[j] += __shfl(p[j], k) * wv;
    }
    float hi[2];
    #pragma unroll
    for (int j = 0; j < 2; ++j) {
        hs[j] = fmaxf(hs[j], 0.f);
        hi[j] = HI[(size_t)(b0 + j) * 64 + lane];
    }
    float h0[2];
    #pragma unroll
    for (int j = 0; j < 2; ++j) h0[j] = bc0[lane];
    for (int k = 0; k < 64; ++k) {
        float w0 = Wc0[k * 64 + lane], w1 = Wc0[(64 + k) * 64 + lane];
        #pragma unroll
        for (int j = 0; j < 2; ++j) h0[j] += __shfl(hi[j], k) * w0 + __shfl(hs[j], k) * w1;
    }
    #pragma unroll
    for (int j = 0; j < 2; ++j) h0[j] = fmaxf(h0[j], 0.f);
    float h1[2];
    #pragma unroll
    for (int j = 0; j < 2; ++j) h1[j] = bc1[lane];
    for (int k = 0; k < 64; ++k) {
        float wv = Wc1[k * 64 + lane];
        #pragma unroll
        for (int j = 0; j < 2; ++j) h1[j] += __shfl(h0[j], k) * wv;
    }
    #pragma unroll
    for (int j = 0; j < 2; ++j) Hout[(size_t)(b0 + j) * 64 + lane] = fmaxf(h1[j], 0.f);
}

// ------------------------------------------------- S4: Z then G (output)
__global__ __launch_bounds__(256) void k_Z_G(
    const float* __restrict__ Qp, const float* __restrict__ sM,
    const int* __restrict__ bi, const float* __restrict__ H,
    const float* __restrict__ W_Z, const float* __restrict__ b_Z,
    const float* __restrict__ Wg0, const float* __restrict__ bg0,
    const float* __restrict__ Wg1, const float* __restrict__ bg1,
    float* __restrict__ G)
{
    float m, inv;
    block_softmax_stats(sM, m, inv);
    int wid = blockIdx.x * 4 + (threadIdx.x >> 6);
    int lane = threadIdx.x & 63;
    int b0 = wid * 2;
    float p[2];
    #pragma unroll
    for (int j = 0; j < 2; ++j) {
        int b = b0 + j;
        int it = bi[b];
        float a = 0.f;
        #pragma unroll
        for (int kz = 0; kz < QKZ; ++kz)
            a += Qp[(size_t)(kz * 8192 + it) * 64 + lane];
        p[j] = a * (__expf(sM[b] - m) * inv);
    }
    float z[2];
    #pragma unroll
    for (int j = 0; j < 2; ++j) z[j] = b_Z[lane];
    for (int k = 0; k < 64; ++k) {
        float wv = W_Z[k * 64 + lane];
        #pragma unroll
        for (int j = 0; j < 2; ++j) z[j] += __shfl(p[j], k) * wv;
    }
    float hr[2];
    #pragma unroll
    for (int j = 0; j < 2; ++j) {
        z[j] = fmaxf(z[j], 0.f);
        hr[j] = H[(size_t)(b0 + j) * 64 + lane];
    }
    float g0[2];
    #pragma unroll
    for (int j = 0; j < 2; ++j) g0[j] = bg0[lane];
    for (int k = 0; k < 64; ++k) {
        float w0 = Wg0[k * 64 + lane], w1 = Wg0[(64 + k) * 64 + lane];
        #pragma unroll
        for (int j = 0; j < 2; ++j) g0[j] += __shfl(hr[j], k) * w0 + __shfl(z[j], k) * w1;
    }
    #pragma unroll
    for (int j = 0; j < 2; ++j) g0[j] = fmaxf(g0[j], 0.f);
    float g1[2];
    #pragma unroll
    for (int j = 0; j < 2; ++j) g1[j] = bg1[lane];
    for (int k = 0; k < 64; ++k) {
        float wv = Wg1[k * 64 + lane];
        #pragma unroll
        for (int j = 0; j < 2; ++j) g1[j] += __shfl(g0[j], k) * wv;
    }
    #pragma unroll
    for (int j = 0; j < 2; ++j) G[(size_t)(b0 + j) * 64 + lane] = fmaxf(g1[j], 0.f);
}

// ---------------------------------------------------------------------------
extern "C" void kernel_launch(void* const* d_in, const int* in_sizes, int n_in,
                              void* d_out, int out_size, void* d_ws, size_t ws_size,
                              hipStream_t stream)
{
    (void)in_sizes; (void)n_in; (void)out_size; (void)ws_size;
    const int*   bu  = (const int*)  d_in[0];
    const int*   bi  = (const int*)  d_in[1];
    const float* R   = (const float*)d_in[2];
    const float* S   = (const float*)d_in[3];
    const float* U   = (const float*)d_in[4];
    const float* V   = (const float*)d_in[5];
    const float* w_r = (const float*)d_in[6];
    const float* b_r = (const float*)d_in[7];
    const float* Wu0 = (const float*)d_in[8];
    const float* bu0 = (const float*)d_in[9];
    const float* Wu1 = (const float*)d_in[10];
    const float* bu1 = (const float*)d_in[11];
    const float* Wv0 = (const float*)d_in[12];
    const float* bv0 = (const float*)d_in[13];
    const float* Wv1 = (const float*)d_in[14];
    const float* bv1 = (const float*)d_in[15];
    const float* Wc0 = (const float*)d_in[16];
    const float* bc0 = (const float*)d_in[17];
    const float* Wc1 = (const float*)d_in[18];
    const float* bc1 = (const float*)d_in[19];
    const float* Wg0 = (const float*)d_in[20];
    const float* bg0 = (const float*)d_in[21];
    const float* Wg1 = (const float*)d_in[22];
    const float* bg1 = (const float*)d_in[23];
    const float* W_I = (const float*)d_in[24];
    const float* b_I = (const float*)d_in[25];
    const float* W_Sm= (const float*)d_in[26];
    const float* b_Sm= (const float*)d_in[27];
    const float* W1A = (const float*)d_in[28];
    const float* b1A = (const float*)d_in[29];
    const float* w2A = (const float*)d_in[30];
    const float* b2A = (const float*)d_in[31];
    const float* W1B = (const float*)d_in[32];
    const float* b1B = (const float*)d_in[33];
    const float* w2B = (const float*)d_in[34];
    const float* b2B = (const float*)d_in[35];
    const float* W1M = (const float*)d_in[36];
    const float* b1M = (const float*)d_in[37];
    const float* w2M = (const float*)d_in[38];
    const float* b2M = (const float*)d_in[39];
    const float* W_Z = (const float*)d_in[40];
    const float* b_Z = (const float*)d_in[41];

    char* ws = (char*)d_ws;
    size_t off = 0;
    float*          Uh  = (float*)(ws + off);          off += 2ull << 20;
    float*          Vh  = (float*)(ws + off);          off += 2ull << 20;
    unsigned short* Uhb = (unsigned short*)(ws + off); off += 1ull << 20;
    unsigned short* Vhb = (unsigned short*)(ws + off); off += 1ull << 20;
    float*          PpI = (float*)(ws + off);          off += (size_t)PKZ << 20;
    float*          PpS = (float*)(ws + off);          off += (size_t)PKZ << 20;
    float*          Qp  = (float*)(ws + off);          off += (size_t)(2 * QKZ) << 20;
    float*          sA  = (float*)(ws + off);
    float*          sM  = sA + 4096;
    float*          sB  = sA + 8192;                   off += 3 * 4096 * 4 + 4096;
    float*          HI  = (float*)(ws + off);          off += 1ull << 20;
    float*          Hh  = (float*)(ws + off);

    k_mlp<<<1024, 256, 0, stream>>>(U, V, w_r, b_r, Wu0, bu0, Wu1, bu1,
                                    Wv0, bv0, Wv1, bv1, Uh, Vh, Uhb, Vhb);
    k_gemm<<<QBLOCKS + PBLOCKS + SBLOCKS, 256, 0, stream>>>(
        R, S, bu, bi, Uhb, Vhb, Uh, Vh,
        W1A, b1A, w2A, b2A, W1M, b1M, w2M, b2M,
        PpI, PpS, Qp, sA, sM);
    k_HI_scoreB<<<512, 256, 0, stream>>>(PpI, sA, bu, Uh, W_I, b_I,
                                         W1B, b1B, w2B, b2B, HI, sB);
    k_HS_H<<<512, 256, 0, stream>>>(PpS, sB, HI, W_Sm, b_Sm, Wc0, bc0, Wc1, bc1,
                                    Hh);
    k_Z_G<<<512, 256, 0, stream>>>(Qp, sM, bi, Hh, W_Z, b_Z, Wg0, bg0, Wg1, bg1,
                                   (float*)d_out);
}